// Round 1
// baseline (121.327 us; speedup 1.0000x reference)
//
#include <hip/hip_runtime.h>
#include <stdint.h>

typedef unsigned short u16;
typedef __bf16 bf16x8 __attribute__((ext_vector_type(8)));
typedef float  f32x4  __attribute__((ext_vector_type(4)));

#define LOG2E 1.44269504088896340736f

__device__ __forceinline__ u16 f2bf(float f) {
  union { float f; unsigned u; } v; v.f = f;
  unsigned r = v.u + 0x7FFFu + ((v.u >> 16) & 1u);
  return (u16)(r >> 16);
}

// ---------------- convert fp32 -> bf16 ----------------
__global__ void k_convert(const float* __restrict__ in, u16* __restrict__ out, int n4) {
  int i = blockIdx.x * 256 + threadIdx.x;
  if (i >= n4) return;
  float4 v = ((const float4*)in)[i];
  uint2 o;
  o.x = (unsigned)f2bf(v.x) | ((unsigned)f2bf(v.y) << 16);
  o.y = (unsigned)f2bf(v.z) | ((unsigned)f2bf(v.w) << 16);
  ((uint2*)out)[i] = o;
}

// ------------- transpose + convert: out[c][r] = in[r][c], in: [R][Cc] fp32 -------------
__global__ void k_transpose(const float* __restrict__ in, u16* __restrict__ out, int R, int Cc) {
  __shared__ u16 tile[64][65];
  int c0 = blockIdx.x * 64, r0 = blockIdx.y * 64;
  int t = threadIdx.x;
  #pragma unroll
  for (int i = 0; i < 16; ++i) {
    int idx = t + i * 256;
    int r = idx >> 6, c = idx & 63;
    tile[c][r] = f2bf(in[(size_t)(r0 + r) * Cc + c0 + c]);
  }
  __syncthreads();
  #pragma unroll
  for (int i = 0; i < 16; ++i) {
    int idx = t + i * 256;
    int r = idx >> 6, c = idx & 63;
    out[(size_t)(c0 + r) * R + r0 + c] = tile[r][c];
  }
}

// swizzle for [rows][32] bf16 tiles (64B rows): chunk = 16B unit 0..3, returns u16 index
__device__ __forceinline__ int swz32(int row, int chunk) {
  return (row * 64 + ((chunk ^ ((row >> 1) & 3)) << 4)) >> 1;
}
// swizzle for [rows][64] bf16 tiles (128B rows): colByte within row, returns u16 index
__device__ __forceinline__ int swz64(int row, int colByte) {
  return (row * 128 + (colByte ^ ((row & 7) << 4))) >> 1;
}

// ---------------- shared GEMM mainloop: C[128x128] tile, K=512, BK=32 ----------------
// A: [M][512] bf16 row-major; Bt: [N][512] bf16 (row = output column)
__device__ __forceinline__ void gemm_core(const u16* __restrict__ A, const u16* __restrict__ Bt,
                                          int m0, int n0, f32x4 (&acc)[4][4],
                                          u16* __restrict__ lA, u16* __restrict__ lB) {
  const int t = threadIdx.x;
  const int lane = t & 63;
  const int w = t >> 6, wr = w >> 1, wc = w & 1;
  const int lr = lane & 15, lg = lane >> 4;
  const int c0 = t, c1 = t + 256;
  const int ar0 = c0 >> 2, ac0 = c0 & 3;
  const int ar1 = c1 >> 2, ac1 = c1 & 3;
  const int sA0 = swz32(ar0, ac0), sA1 = swz32(ar1, ac1);
  #pragma unroll 1
  for (int k0 = 0; k0 < 512; k0 += 32) {
    uint4 a0 = *(const uint4*)(A + (size_t)(m0 + ar0) * 512 + k0 + ac0 * 8);
    uint4 a1 = *(const uint4*)(A + (size_t)(m0 + ar1) * 512 + k0 + ac1 * 8);
    uint4 b0 = *(const uint4*)(Bt + (size_t)(n0 + ar0) * 512 + k0 + ac0 * 8);
    uint4 b1 = *(const uint4*)(Bt + (size_t)(n0 + ar1) * 512 + k0 + ac1 * 8);
    __syncthreads();
    *(uint4*)&lA[sA0] = a0; *(uint4*)&lA[sA1] = a1;
    *(uint4*)&lB[sA0] = b0; *(uint4*)&lB[sA1] = b1;
    __syncthreads();
    bf16x8 af[4], bfr[4];
    #pragma unroll
    for (int i = 0; i < 4; ++i)
      af[i] = __builtin_bit_cast(bf16x8, *(const uint4*)&lA[swz32(wr * 64 + i * 16 + lr, lg)]);
    #pragma unroll
    for (int j = 0; j < 4; ++j)
      bfr[j] = __builtin_bit_cast(bf16x8, *(const uint4*)&lB[swz32(wc * 64 + j * 16 + lr, lg)]);
    #pragma unroll
    for (int i = 0; i < 4; ++i)
      #pragma unroll
      for (int j = 0; j < 4; ++j)
        acc[i][j] = __builtin_amdgcn_mfma_f32_16x16x32_bf16(af[i], bfr[j], acc[i][j], 0, 0, 0);
  }
}

// ---------------- QKV GEMM + scatter into Q (scaled), K, V^T ----------------
__global__ __launch_bounds__(256, 2) void k_gemm_qkv(const u16* __restrict__ A, const u16* __restrict__ Bt,
                                                     const float* __restrict__ bias,
                                                     u16* __restrict__ Qb, u16* __restrict__ Kb,
                                                     u16* __restrict__ Vtb) {
  __shared__ __align__(16) u16 lA[128 * 32];
  __shared__ __align__(16) u16 lB[128 * 32];
  f32x4 acc[4][4];
  #pragma unroll
  for (int i = 0; i < 4; ++i)
    #pragma unroll
    for (int j = 0; j < 4; ++j) acc[i][j] = (f32x4){0.f, 0.f, 0.f, 0.f};
  const int m0 = blockIdx.x * 128, n0 = blockIdx.y * 128;
  gemm_core(A, Bt, m0, n0, acc, lA, lB);
  const int lane = threadIdx.x & 63;
  const int w = threadIdx.x >> 6, wr = w >> 1, wc = w & 1;
  const int lr = lane & 15, lg = lane >> 4;
  #pragma unroll
  for (int i = 0; i < 4; ++i)
    #pragma unroll
    for (int j = 0; j < 4; ++j)
      #pragma unroll
      for (int r = 0; r < 4; ++r) {
        int m = m0 + wr * 64 + i * 16 + lg * 4 + r;
        int n = n0 + wc * 64 + j * 16 + lr;
        float val = acc[i][j][r] + bias[n];
        int b = m >> 11, npos = m & 2047;
        int which = n >> 9, h = (n >> 6) & 7, hd = n & 63;
        size_t bh = (size_t)(b * 8 + h);
        if (which == 0)      Qb[(bh * 2048 + npos) * 64 + hd] = f2bf(val * 0.125f);
        else if (which == 1) Kb[(bh * 2048 + npos) * 64 + hd] = f2bf(val);
        else                 Vtb[(bh * 64 + hd) * 2048 + npos] = f2bf(val);
      }
}

// ---------------- proj GEMM -> fp32 output ----------------
__global__ __launch_bounds__(256, 2) void k_gemm_proj(const u16* __restrict__ A, const u16* __restrict__ Bt,
                                                      const float* __restrict__ bias,
                                                      float* __restrict__ out) {
  __shared__ __align__(16) u16 lA[128 * 32];
  __shared__ __align__(16) u16 lB[128 * 32];
  f32x4 acc[4][4];
  #pragma unroll
  for (int i = 0; i < 4; ++i)
    #pragma unroll
    for (int j = 0; j < 4; ++j) acc[i][j] = (f32x4){0.f, 0.f, 0.f, 0.f};
  const int m0 = blockIdx.x * 128, n0 = blockIdx.y * 128;
  gemm_core(A, Bt, m0, n0, acc, lA, lB);
  const int lane = threadIdx.x & 63;
  const int w = threadIdx.x >> 6, wr = w >> 1, wc = w & 1;
  const int lr = lane & 15, lg = lane >> 4;
  #pragma unroll
  for (int i = 0; i < 4; ++i)
    #pragma unroll
    for (int j = 0; j < 4; ++j)
      #pragma unroll
      for (int r = 0; r < 4; ++r) {
        int m = m0 + wr * 64 + i * 16 + lg * 4 + r;
        int n = n0 + wc * 64 + j * 16 + lr;
        out[(size_t)m * 512 + n] = acc[i][j][r] + bias[n];
      }
}

// ---------------- flash attention: block = (64 q-rows, one bh); 4 waves x 16 rows ----------------
__global__ __launch_bounds__(256, 2) void k_attn(const u16* __restrict__ Qb, const u16* __restrict__ Kb,
                                                 const u16* __restrict__ Vtb, u16* __restrict__ AO) {
  __shared__ __align__(16) u16 Kt[64 * 64];      // [s][hd], swizzled
  __shared__ __align__(16) u16 Vl[64 * 64];      // [hd][s], swizzled
  __shared__ __align__(16) u16 Pl[4][16 * 64];   // per-wave P tile [qrow][s], swizzled
  const int t = threadIdx.x;
  const int lane = t & 63, w = t >> 6;
  const int lr = lane & 15, lg = lane >> 4;
  const int qtile = blockIdx.x, bh = blockIdx.y;
  const int q0 = qtile * 64 + w * 16;

  bf16x8 qf0, qf1;
  {
    const u16* qrow = Qb + ((size_t)bh * 2048 + q0 + lr) * 64;
    qf0 = __builtin_bit_cast(bf16x8, *(const uint4*)(qrow + lg * 8));
    qf1 = __builtin_bit_cast(bf16x8, *(const uint4*)(qrow + 32 + lg * 8));
  }

  float m_run[4], l_run[4];
  f32x4 oacc[4];
  #pragma unroll
  for (int r = 0; r < 4; ++r) { m_run[r] = -1e30f; l_run[r] = 0.f; }
  #pragma unroll
  for (int f = 0; f < 4; ++f) oacc[f] = (f32x4){0.f, 0.f, 0.f, 0.f};

  const int c0 = t, c1 = t + 256;
  const int r0_ = c0 >> 3, o0 = (c0 & 7) << 3;
  const int r1_ = c1 >> 3, o1 = (c1 & 7) << 3;
  const int s0i = swz64(r0_, o0 * 2), s1i = swz64(r1_, o1 * 2);
  const u16* Kbase = Kb + (size_t)bh * 2048 * 64;
  const u16* Vbase = Vtb + (size_t)bh * 64 * 2048;
  u16* pw = Pl[w];

  #pragma unroll 1
  for (int s0 = 0; s0 < 2048; s0 += 64) {
    uint4 kq0 = *(const uint4*)(Kbase + (size_t)(s0 + r0_) * 64 + o0);
    uint4 kq1 = *(const uint4*)(Kbase + (size_t)(s0 + r1_) * 64 + o1);
    uint4 vq0 = *(const uint4*)(Vbase + (size_t)r0_ * 2048 + s0 + o0);
    uint4 vq1 = *(const uint4*)(Vbase + (size_t)r1_ * 2048 + s0 + o1);
    __syncthreads();
    *(uint4*)&Kt[s0i] = kq0; *(uint4*)&Kt[s1i] = kq1;
    *(uint4*)&Vl[s0i] = vq0; *(uint4*)&Vl[s1i] = vq1;
    __syncthreads();

    // S = Q K^T  (Q pre-scaled)
    f32x4 sa[4];
    #pragma unroll
    for (int jf = 0; jf < 4; ++jf) {
      bf16x8 kb0 = __builtin_bit_cast(bf16x8, *(const uint4*)&Kt[swz64(jf * 16 + lr, lg * 16)]);
      bf16x8 kb1 = __builtin_bit_cast(bf16x8, *(const uint4*)&Kt[swz64(jf * 16 + lr, 64 + lg * 16)]);
      f32x4 z = (f32x4){0.f, 0.f, 0.f, 0.f};
      z = __builtin_amdgcn_mfma_f32_16x16x32_bf16(qf0, kb0, z, 0, 0, 0);
      z = __builtin_amdgcn_mfma_f32_16x16x32_bf16(qf1, kb1, z, 0, 0, 0);
      sa[jf] = z;
    }

    // online softmax (rows r of this lane's 16-lane group)
    float tm[4], fac[4], mnew[4], rs[4];
    #pragma unroll
    for (int r = 0; r < 4; ++r)
      tm[r] = fmaxf(fmaxf(sa[0][r], sa[1][r]), fmaxf(sa[2][r], sa[3][r]));
    #pragma unroll
    for (int r = 0; r < 4; ++r) {
      tm[r] = fmaxf(tm[r], __shfl_xor(tm[r], 1));
      tm[r] = fmaxf(tm[r], __shfl_xor(tm[r], 2));
      tm[r] = fmaxf(tm[r], __shfl_xor(tm[r], 4));
      tm[r] = fmaxf(tm[r], __shfl_xor(tm[r], 8));
    }
    #pragma unroll
    for (int r = 0; r < 4; ++r) {
      mnew[r] = fmaxf(m_run[r], tm[r]);
      fac[r] = exp2f((m_run[r] - mnew[r]) * LOG2E);
      m_run[r] = mnew[r];
      rs[r] = 0.f;
    }
    f32x4 p[4];
    #pragma unroll
    for (int jf = 0; jf < 4; ++jf)
      #pragma unroll
      for (int r = 0; r < 4; ++r) {
        float pv = exp2f((sa[jf][r] - mnew[r]) * LOG2E);
        p[jf][r] = pv;
        rs[r] += pv;
      }
    #pragma unroll
    for (int r = 0; r < 4; ++r) {
      rs[r] += __shfl_xor(rs[r], 1);
      rs[r] += __shfl_xor(rs[r], 2);
      rs[r] += __shfl_xor(rs[r], 4);
      rs[r] += __shfl_xor(rs[r], 8);
      l_run[r] = l_run[r] * fac[r] + rs[r];
    }
    #pragma unroll
    for (int f = 0; f < 4; ++f)
      #pragma unroll
      for (int r = 0; r < 4; ++r) oacc[f][r] *= fac[r];

    // P (D-layout) -> per-wave LDS (A-layout source)
    #pragma unroll
    for (int jf = 0; jf < 4; ++jf)
      #pragma unroll
      for (int r = 0; r < 4; ++r)
        pw[swz64(lg * 4 + r, (jf * 16 + lr) * 2)] = f2bf(p[jf][r]);
    asm volatile("s_waitcnt lgkmcnt(0)" ::: "memory");

    // O += P V
    #pragma unroll
    for (int kf = 0; kf < 2; ++kf) {
      bf16x8 pa = __builtin_bit_cast(bf16x8, *(const uint4*)&pw[swz64(lr, kf * 64 + lg * 16)]);
      #pragma unroll
      for (int f = 0; f < 4; ++f) {
        bf16x8 vb = __builtin_bit_cast(bf16x8, *(const uint4*)&Vl[swz64(f * 16 + lr, kf * 64 + lg * 16)]);
        oacc[f] = __builtin_amdgcn_mfma_f32_16x16x32_bf16(pa, vb, oacc[f], 0, 0, 0);
      }
    }
  }

  const int b = bh >> 3, h = bh & 7;
  #pragma unroll
  for (int r = 0; r < 4; ++r) {
    float inv = 1.0f / l_run[r];
    int qrow = q0 + lg * 4 + r;
    #pragma unroll
    for (int f = 0; f < 4; ++f)
      AO[((size_t)b * 2048 + qrow) * 512 + h * 64 + f * 16 + lr] = f2bf(oacc[f][r] * inv);
  }
}

extern "C" void kernel_launch(void* const* d_in, const int* in_sizes, int n_in,
                              void* d_out, int out_size, void* d_ws, size_t ws_size,
                              hipStream_t stream) {
  (void)in_sizes; (void)n_in; (void)out_size; (void)ws_size;
  const float* x      = (const float*)d_in[0];
  const float* qkv_w  = (const float*)d_in[1];
  const float* qkv_b  = (const float*)d_in[2];
  const float* proj_w = (const float*)d_in[3];
  const float* proj_b = (const float*)d_in[4];
  float* out = (float*)d_out;
  char* wsc = (char*)d_ws;
  u16* Xb  = (u16*)(wsc + 0);          // 4096x512 bf16        (4,194,304 B)
  u16* Wt  = (u16*)(wsc + 4194304);    // 1536x512 bf16 (W^T)  (1,572,864 B)
  u16* Pt  = (u16*)(wsc + 5767168);    // 512x512 bf16 (W^T)   (  524,288 B)
  u16* Qb  = (u16*)(wsc + 6291456);    // [16][2048][64] bf16  (4,194,304 B)
  u16* Kb  = (u16*)(wsc + 10485760);   // [16][2048][64] bf16
  u16* Vtb = (u16*)(wsc + 14680064);   // [16][64][2048] bf16
  u16* AO  = (u16*)(wsc + 18874368);   // 4096x512 bf16

  k_convert<<<2048, 256, 0, stream>>>(x, Xb, 524288);
  k_transpose<<<dim3(24, 8), 256, 0, stream>>>(qkv_w, Wt, 512, 1536);
  k_transpose<<<dim3(8, 8), 256, 0, stream>>>(proj_w, Pt, 512, 512);
  k_gemm_qkv<<<dim3(32, 12), 256, 0, stream>>>(Xb, Wt, qkv_b, Qb, Kb, Vtb);
  k_attn<<<dim3(32, 16), 256, 0, stream>>>(Qb, Kb, Vtb, AO);
  k_gemm_proj<<<dim3(32, 4), 256, 0, stream>>>(AO, Pt, proj_b, out);
}

// Round 2
// 112.303 us; speedup vs baseline: 1.0803x; 1.0803x over previous
//
#include <hip/hip_runtime.h>
#include <stdint.h>

typedef unsigned short u16;
typedef __bf16 bf16x8 __attribute__((ext_vector_type(8)));
typedef float  f32x4  __attribute__((ext_vector_type(4)));

#define LOG2E 1.44269504088896340736f

__device__ __forceinline__ u16 f2bf(float f) {
  union { float f; unsigned u; } v; v.f = f;
  unsigned r = v.u + 0x7FFFu + ((v.u >> 16) & 1u);
  return (u16)(r >> 16);
}

// ---------------- convert fp32 -> bf16 ----------------
__global__ void k_convert(const float* __restrict__ in, u16* __restrict__ out, int n4) {
  int i = blockIdx.x * 256 + threadIdx.x;
  if (i >= n4) return;
  float4 v = ((const float4*)in)[i];
  uint2 o;
  o.x = (unsigned)f2bf(v.x) | ((unsigned)f2bf(v.y) << 16);
  o.y = (unsigned)f2bf(v.z) | ((unsigned)f2bf(v.w) << 16);
  ((uint2*)out)[i] = o;
}

// ------------- transpose + convert: out[c][r] = in[r][c], in: [R][Cc] fp32 -------------
__global__ void k_transpose(const float* __restrict__ in, u16* __restrict__ out, int R, int Cc) {
  __shared__ u16 tile[64][65];
  int c0 = blockIdx.x * 64, r0 = blockIdx.y * 64;
  int t = threadIdx.x;
  #pragma unroll
  for (int i = 0; i < 16; ++i) {
    int idx = t + i * 256;
    int r = idx >> 6, c = idx & 63;
    tile[c][r] = f2bf(in[(size_t)(r0 + r) * Cc + c0 + c]);
  }
  __syncthreads();
  #pragma unroll
  for (int i = 0; i < 16; ++i) {
    int idx = t + i * 256;
    int r = idx >> 6, c = idx & 63;
    out[(size_t)(c0 + r) * R + r0 + c] = tile[r][c];
  }
}

// swizzle for [rows][32] bf16 tiles (64B rows): chunk = 16B unit 0..3, returns u16 index
__device__ __forceinline__ int swz32(int row, int chunk) {
  return (row * 64 + ((chunk ^ ((row >> 1) & 3)) << 4)) >> 1;
}
// swizzle for [rows][64] bf16 tiles (128B rows): colByte within row, returns u16 index
__device__ __forceinline__ int swz64(int row, int colByte) {
  return (row * 128 + (colByte ^ ((row & 7) << 4))) >> 1;
}

// ---------------- shared GEMM mainloop: C[128x128] tile, K=512, BK=32 ----------------
__device__ __forceinline__ void gemm_core(const u16* __restrict__ A, const u16* __restrict__ Bt,
                                          int m0, int n0, f32x4 (&acc)[4][4],
                                          u16* __restrict__ lA, u16* __restrict__ lB) {
  const int t = threadIdx.x;
  const int lane = t & 63;
  const int w = t >> 6, wr = w >> 1, wc = w & 1;
  const int lr = lane & 15, lg = lane >> 4;
  const int c0 = t, c1 = t + 256;
  const int ar0 = c0 >> 2, ac0 = c0 & 3;
  const int ar1 = c1 >> 2, ac1 = c1 & 3;
  const int sA0 = swz32(ar0, ac0), sA1 = swz32(ar1, ac1);
  #pragma unroll 1
  for (int k0 = 0; k0 < 512; k0 += 32) {
    uint4 a0 = *(const uint4*)(A + (size_t)(m0 + ar0) * 512 + k0 + ac0 * 8);
    uint4 a1 = *(const uint4*)(A + (size_t)(m0 + ar1) * 512 + k0 + ac1 * 8);
    uint4 b0 = *(const uint4*)(Bt + (size_t)(n0 + ar0) * 512 + k0 + ac0 * 8);
    uint4 b1 = *(const uint4*)(Bt + (size_t)(n0 + ar1) * 512 + k0 + ac1 * 8);
    __syncthreads();
    *(uint4*)&lA[sA0] = a0; *(uint4*)&lA[sA1] = a1;
    *(uint4*)&lB[sA0] = b0; *(uint4*)&lB[sA1] = b1;
    __syncthreads();
    bf16x8 af[4], bfr[4];
    #pragma unroll
    for (int i = 0; i < 4; ++i)
      af[i] = __builtin_bit_cast(bf16x8, *(const uint4*)&lA[swz32(wr * 64 + i * 16 + lr, lg)]);
    #pragma unroll
    for (int j = 0; j < 4; ++j)
      bfr[j] = __builtin_bit_cast(bf16x8, *(const uint4*)&lB[swz32(wc * 64 + j * 16 + lr, lg)]);
    #pragma unroll
    for (int i = 0; i < 4; ++i)
      #pragma unroll
      for (int j = 0; j < 4; ++j)
        acc[i][j] = __builtin_amdgcn_mfma_f32_16x16x32_bf16(af[i], bfr[j], acc[i][j], 0, 0, 0);
  }
}

// ---------------- QKV GEMM + scatter into Q (scaled), K, V^T ----------------
__global__ __launch_bounds__(256, 2) void k_gemm_qkv(const u16* __restrict__ A, const u16* __restrict__ Bt,
                                                     const float* __restrict__ bias,
                                                     u16* __restrict__ Qb, u16* __restrict__ Kb,
                                                     u16* __restrict__ Vtb) {
  __shared__ __align__(16) u16 lA[128 * 32];
  __shared__ __align__(16) u16 lB[128 * 32];
  f32x4 acc[4][4];
  #pragma unroll
  for (int i = 0; i < 4; ++i)
    #pragma unroll
    for (int j = 0; j < 4; ++j) acc[i][j] = (f32x4){0.f, 0.f, 0.f, 0.f};
  const int m0 = blockIdx.x * 128, n0 = blockIdx.y * 128;
  gemm_core(A, Bt, m0, n0, acc, lA, lB);
  const int lane = threadIdx.x & 63;
  const int w = threadIdx.x >> 6, wr = w >> 1, wc = w & 1;
  const int lr = lane & 15, lg = lane >> 4;
  #pragma unroll
  for (int i = 0; i < 4; ++i)
    #pragma unroll
    for (int j = 0; j < 4; ++j)
      #pragma unroll
      for (int r = 0; r < 4; ++r) {
        int m = m0 + wr * 64 + i * 16 + lg * 4 + r;
        int n = n0 + wc * 64 + j * 16 + lr;
        float val = acc[i][j][r] + bias[n];
        int b = m >> 11, npos = m & 2047;
        int which = n >> 9, h = (n >> 6) & 7, hd = n & 63;
        size_t bh = (size_t)(b * 8 + h);
        if (which == 0)      Qb[(bh * 2048 + npos) * 64 + hd] = f2bf(val * 0.125f);
        else if (which == 1) Kb[(bh * 2048 + npos) * 64 + hd] = f2bf(val);
        else                 Vtb[(bh * 64 + hd) * 2048 + npos] = f2bf(val);
      }
}

// ---------------- proj GEMM -> fp32 output ----------------
__global__ __launch_bounds__(256, 2) void k_gemm_proj(const u16* __restrict__ A, const u16* __restrict__ Bt,
                                                      const float* __restrict__ bias,
                                                      float* __restrict__ out) {
  __shared__ __align__(16) u16 lA[128 * 32];
  __shared__ __align__(16) u16 lB[128 * 32];
  f32x4 acc[4][4];
  #pragma unroll
  for (int i = 0; i < 4; ++i)
    #pragma unroll
    for (int j = 0; j < 4; ++j) acc[i][j] = (f32x4){0.f, 0.f, 0.f, 0.f};
  const int m0 = blockIdx.x * 128, n0 = blockIdx.y * 128;
  gemm_core(A, Bt, m0, n0, acc, lA, lB);
  const int lane = threadIdx.x & 63;
  const int w = threadIdx.x >> 6, wr = w >> 1, wc = w & 1;
  const int lr = lane & 15, lg = lane >> 4;
  #pragma unroll
  for (int i = 0; i < 4; ++i)
    #pragma unroll
    for (int j = 0; j < 4; ++j)
      #pragma unroll
      for (int r = 0; r < 4; ++r) {
        int m = m0 + wr * 64 + i * 16 + lg * 4 + r;
        int n = n0 + wc * 64 + j * 16 + lr;
        out[(size_t)m * 512 + n] = acc[i][j][r] + bias[n];
      }
}

// ---------------- flash attention with KV-split: block = (64 q-rows, one bh, one split) ----
// Writes unnormalized O partials (fp32) + per-row m,l. Split covers 1024 s (16 tiles).
__global__ __launch_bounds__(256, 4) void k_attn(const u16* __restrict__ Qb, const u16* __restrict__ Kb,
                                                 const u16* __restrict__ Vtb,
                                                 float* __restrict__ Op, float* __restrict__ Mp,
                                                 float* __restrict__ Lp) {
  __shared__ __align__(16) u16 Kt[64 * 64];      // [s][hd], swizzled
  __shared__ __align__(16) u16 Vl[64 * 64];      // [hd][s], swizzled
  __shared__ __align__(16) u16 Pl[4][16 * 64];   // per-wave P tile [qrow][s], swizzled
  const int t = threadIdx.x;
  const int lane = t & 63, w = t >> 6;
  const int lr = lane & 15, lg = lane >> 4;
  const int qtile = blockIdx.x, bh = blockIdx.y, split = blockIdx.z;
  const int q0 = qtile * 64 + w * 16;
  const int sBeg = split * 1024;

  bf16x8 qf0, qf1;
  {
    const u16* qrow = Qb + ((size_t)bh * 2048 + q0 + lr) * 64;
    qf0 = __builtin_bit_cast(bf16x8, *(const uint4*)(qrow + lg * 8));
    qf1 = __builtin_bit_cast(bf16x8, *(const uint4*)(qrow + 32 + lg * 8));
  }

  float m_run[4], l_run[4];
  f32x4 oacc[4];
  #pragma unroll
  for (int r = 0; r < 4; ++r) { m_run[r] = -1e30f; l_run[r] = 0.f; }
  #pragma unroll
  for (int f = 0; f < 4; ++f) oacc[f] = (f32x4){0.f, 0.f, 0.f, 0.f};

  const int c0 = t, c1 = t + 256;
  const int r0_ = c0 >> 3, o0 = (c0 & 7) << 3;
  const int r1_ = c1 >> 3, o1 = (c1 & 7) << 3;
  const int s0i = swz64(r0_, o0 * 2), s1i = swz64(r1_, o1 * 2);
  const u16* Kbase = Kb + (size_t)bh * 2048 * 64;
  const u16* Vbase = Vtb + (size_t)bh * 64 * 2048;
  u16* pw = Pl[w];

  // prologue: prefetch tile 0 into registers
  uint4 kq0 = *(const uint4*)(Kbase + (size_t)(sBeg + r0_) * 64 + o0);
  uint4 kq1 = *(const uint4*)(Kbase + (size_t)(sBeg + r1_) * 64 + o1);
  uint4 vq0 = *(const uint4*)(Vbase + (size_t)r0_ * 2048 + sBeg + o0);
  uint4 vq1 = *(const uint4*)(Vbase + (size_t)r1_ * 2048 + sBeg + o1);

  #pragma unroll 1
  for (int s0 = sBeg; s0 < sBeg + 1024; s0 += 64) {
    __syncthreads();
    *(uint4*)&Kt[s0i] = kq0; *(uint4*)&Kt[s1i] = kq1;
    *(uint4*)&Vl[s0i] = vq0; *(uint4*)&Vl[s1i] = vq1;
    __syncthreads();
    // prefetch next tile into registers — latency hides under this tile's compute
    if (s0 + 64 < sBeg + 1024) {
      int sn = s0 + 64;
      kq0 = *(const uint4*)(Kbase + (size_t)(sn + r0_) * 64 + o0);
      kq1 = *(const uint4*)(Kbase + (size_t)(sn + r1_) * 64 + o1);
      vq0 = *(const uint4*)(Vbase + (size_t)r0_ * 2048 + sn + o0);
      vq1 = *(const uint4*)(Vbase + (size_t)r1_ * 2048 + sn + o1);
    }

    // S = Q K^T  (Q pre-scaled)
    f32x4 sa[4];
    #pragma unroll
    for (int jf = 0; jf < 4; ++jf) {
      bf16x8 kb0 = __builtin_bit_cast(bf16x8, *(const uint4*)&Kt[swz64(jf * 16 + lr, lg * 16)]);
      bf16x8 kb1 = __builtin_bit_cast(bf16x8, *(const uint4*)&Kt[swz64(jf * 16 + lr, 64 + lg * 16)]);
      f32x4 z = (f32x4){0.f, 0.f, 0.f, 0.f};
      z = __builtin_amdgcn_mfma_f32_16x16x32_bf16(qf0, kb0, z, 0, 0, 0);
      z = __builtin_amdgcn_mfma_f32_16x16x32_bf16(qf1, kb1, z, 0, 0, 0);
      sa[jf] = z;
    }

    // online softmax (rows r of this lane's 16-lane group)
    float tm[4], fac[4], mnew[4], rs[4];
    #pragma unroll
    for (int r = 0; r < 4; ++r)
      tm[r] = fmaxf(fmaxf(sa[0][r], sa[1][r]), fmaxf(sa[2][r], sa[3][r]));
    #pragma unroll
    for (int r = 0; r < 4; ++r) {
      tm[r] = fmaxf(tm[r], __shfl_xor(tm[r], 1));
      tm[r] = fmaxf(tm[r], __shfl_xor(tm[r], 2));
      tm[r] = fmaxf(tm[r], __shfl_xor(tm[r], 4));
      tm[r] = fmaxf(tm[r], __shfl_xor(tm[r], 8));
    }
    #pragma unroll
    for (int r = 0; r < 4; ++r) {
      mnew[r] = fmaxf(m_run[r], tm[r]);
      fac[r] = exp2f((m_run[r] - mnew[r]) * LOG2E);
      m_run[r] = mnew[r];
      rs[r] = 0.f;
    }
    f32x4 p[4];
    #pragma unroll
    for (int jf = 0; jf < 4; ++jf)
      #pragma unroll
      for (int r = 0; r < 4; ++r) {
        float pv = exp2f((sa[jf][r] - mnew[r]) * LOG2E);
        p[jf][r] = pv;
        rs[r] += pv;
      }
    #pragma unroll
    for (int r = 0; r < 4; ++r) {
      rs[r] += __shfl_xor(rs[r], 1);
      rs[r] += __shfl_xor(rs[r], 2);
      rs[r] += __shfl_xor(rs[r], 4);
      rs[r] += __shfl_xor(rs[r], 8);
      l_run[r] = l_run[r] * fac[r] + rs[r];
    }
    #pragma unroll
    for (int f = 0; f < 4; ++f)
      #pragma unroll
      for (int r = 0; r < 4; ++r) oacc[f][r] *= fac[r];

    // P (D-layout) -> per-wave LDS (A-layout source)
    #pragma unroll
    for (int jf = 0; jf < 4; ++jf)
      #pragma unroll
      for (int r = 0; r < 4; ++r)
        pw[swz64(lg * 4 + r, (jf * 16 + lr) * 2)] = f2bf(p[jf][r]);
    asm volatile("s_waitcnt lgkmcnt(0)" ::: "memory");

    // O += P V
    #pragma unroll
    for (int kf = 0; kf < 2; ++kf) {
      bf16x8 pa = __builtin_bit_cast(bf16x8, *(const uint4*)&pw[swz64(lr, kf * 64 + lg * 16)]);
      #pragma unroll
      for (int f = 0; f < 4; ++f) {
        bf16x8 vb = __builtin_bit_cast(bf16x8, *(const uint4*)&Vl[swz64(f * 16 + lr, kf * 64 + lg * 16)]);
        oacc[f] = __builtin_amdgcn_mfma_f32_16x16x32_bf16(pa, vb, oacc[f], 0, 0, 0);
      }
    }
  }

  // epilogue: unnormalized partials
  const size_t rbase = (size_t)(split * 16 + bh) * 2048;
  #pragma unroll
  for (int r = 0; r < 4; ++r) {
    int qrow = q0 + lg * 4 + r;
    #pragma unroll
    for (int f = 0; f < 4; ++f)
      Op[(rbase + qrow) * 64 + f * 16 + lr] = oacc[f][r];
    if (lr == 0) {
      Mp[rbase + qrow] = m_run[r];
      Lp[rbase + qrow] = l_run[r];
    }
  }
}

// ---------------- combine 2 KV-splits -> AO (bf16, [b][q][h*64+hd]) ----------------
__global__ void k_combine(const float* __restrict__ Op, const float* __restrict__ Mp,
                          const float* __restrict__ Lp, u16* __restrict__ AO) {
  int idx = blockIdx.x * 256 + threadIdx.x;  // 32768 rows * 16 chunks
  int chunk = idx & 15;
  int row = idx >> 4;                        // bh*2048 + q
  float m0 = Mp[row], m1 = Mp[32768 + row];
  float l0 = Lp[row], l1 = Lp[32768 + row];
  float M = fmaxf(m0, m1);
  float w0 = exp2f((m0 - M) * LOG2E), w1 = exp2f((m1 - M) * LOG2E);
  float inv = 1.0f / (w0 * l0 + w1 * l1);
  float4 o0 = ((const float4*)Op)[row * 16 + chunk];
  float4 o1 = ((const float4*)Op)[32768 * 16 + row * 16 + chunk];
  float x0 = (w0 * o0.x + w1 * o1.x) * inv;
  float x1 = (w0 * o0.y + w1 * o1.y) * inv;
  float x2 = (w0 * o0.z + w1 * o1.z) * inv;
  float x3 = (w0 * o0.w + w1 * o1.w) * inv;
  int bh = row >> 11, q = row & 2047;
  int b = bh >> 3, h = bh & 7;
  size_t dst = (size_t)(b * 2048 + q) * 512 + h * 64 + chunk * 4;
  uint2 pk;
  pk.x = (unsigned)f2bf(x0) | ((unsigned)f2bf(x1) << 16);
  pk.y = (unsigned)f2bf(x2) | ((unsigned)f2bf(x3) << 16);
  *(uint2*)(AO + dst) = pk;
}

extern "C" void kernel_launch(void* const* d_in, const int* in_sizes, int n_in,
                              void* d_out, int out_size, void* d_ws, size_t ws_size,
                              hipStream_t stream) {
  (void)in_sizes; (void)n_in; (void)out_size; (void)ws_size;
  const float* x      = (const float*)d_in[0];
  const float* qkv_w  = (const float*)d_in[1];
  const float* qkv_b  = (const float*)d_in[2];
  const float* proj_w = (const float*)d_in[3];
  const float* proj_b = (const float*)d_in[4];
  float* out = (float*)d_out;
  char* wsc = (char*)d_ws;
  u16*   Xb  = (u16*)(wsc + 0);          // 4096x512 bf16        (4,194,304 B)
  u16*   Wt  = (u16*)(wsc + 4194304);    // 1536x512 bf16 (W^T)  (1,572,864 B)
  u16*   Pt  = (u16*)(wsc + 5767168);    // 512x512 bf16 (W^T)   (  524,288 B)
  u16*   Qb  = (u16*)(wsc + 6291456);    // [16][2048][64] bf16  (4,194,304 B)
  u16*   Kb  = (u16*)(wsc + 10485760);   // [16][2048][64] bf16
  u16*   Vtb = (u16*)(wsc + 14680064);   // [16][64][2048] bf16
  u16*   AO  = (u16*)(wsc + 18874368);   // 4096x512 bf16
  float* Op  = (float*)(wsc + 23068672); // [2][16][2048][64] f32 (16,777,216 B)
  float* Mp  = (float*)(wsc + 39845888); // [2][16][2048] f32     (   262,144 B)
  float* Lp  = (float*)(wsc + 40108032); // [2][16][2048] f32     (   262,144 B)

  k_convert<<<2048, 256, 0, stream>>>(x, Xb, 524288);
  k_transpose<<<dim3(24, 8), 256, 0, stream>>>(qkv_w, Wt, 512, 1536);
  k_transpose<<<dim3(8, 8), 256, 0, stream>>>(proj_w, Pt, 512, 512);
  k_gemm_qkv<<<dim3(32, 12), 256, 0, stream>>>(Xb, Wt, qkv_b, Qb, Kb, Vtb);
  k_attn<<<dim3(32, 16, 2), 256, 0, stream>>>(Qb, Kb, Vtb, Op, Mp, Lp);
  k_combine<<<2048, 256, 0, stream>>>(Op, Mp, Lp, AO);
  k_gemm_proj<<<dim3(32, 4), 256, 0, stream>>>(AO, Pt, proj_b, out);
}

// Round 3
// 81.360 us; speedup vs baseline: 1.4912x; 1.3803x over previous
//
#include <hip/hip_runtime.h>
#include <stdint.h>

typedef unsigned short u16;
typedef __bf16 bf16x8 __attribute__((ext_vector_type(8)));
typedef __bf16 bf16x4 __attribute__((ext_vector_type(4)));
typedef _Float16 f16x4 __attribute__((ext_vector_type(4)));
typedef _Float16 f16x8 __attribute__((ext_vector_type(8)));
typedef float  f32x4  __attribute__((ext_vector_type(4)));

__device__ __forceinline__ u16 f2bf(float f) {
  union { float f; unsigned u; } v; v.f = f;
  unsigned r = v.u + 0x7FFFu + ((v.u >> 16) & 1u);
  return (u16)(r >> 16);
}

__device__ __forceinline__ void gload16(const void* g, void* l) {
  __builtin_amdgcn_global_load_lds((const __attribute__((address_space(1))) unsigned int*)g,
                                   (__attribute__((address_space(3))) unsigned int*)l, 16, 0, 0);
}

// ---------------- fused prep: x->bf16 convert + both weight transposes ----------------
__global__ void k_prep(const float* __restrict__ x, const float* __restrict__ qw,
                       const float* __restrict__ pjw, u16* __restrict__ Xb,
                       u16* __restrict__ Wt, u16* __restrict__ Pt) {
  __shared__ u16 tile[64][65];
  const int b = blockIdx.x, t = threadIdx.x;
  if (b < 2048) {
    int i = b * 256 + t;
    float4 v = ((const float4*)x)[i];
    uint2 o;
    o.x = (unsigned)f2bf(v.x) | ((unsigned)f2bf(v.y) << 16);
    o.y = (unsigned)f2bf(v.z) | ((unsigned)f2bf(v.w) << 16);
    ((uint2*)Xb)[i] = o;
    return;
  }
  const float* in; u16* out; int Cc, bx, by;
  if (b < 2240) { in = qw;  out = Wt; Cc = 1536; bx = (b - 2048) % 24; by = (b - 2048) / 24; }
  else          { in = pjw; out = Pt; Cc = 512;  bx = (b - 2240) & 7;  by = (b - 2240) >> 3; }
  const int c0 = bx * 64, r0 = by * 64;
  #pragma unroll
  for (int i = 0; i < 16; ++i) {
    int idx = t + i * 256;
    int r = idx >> 6, c = idx & 63;
    tile[c][r] = f2bf(in[(size_t)(r0 + r) * Cc + c0 + c]);
  }
  __syncthreads();
  #pragma unroll
  for (int i = 0; i < 16; ++i) {
    int idx = t + i * 256;
    int r = idx >> 6, c = idx & 63;
    out[(size_t)(c0 + r) * 512 + r0 + c] = tile[r][c];
  }
}

// swizzle for [rows][32] bf16 tiles: chunk 0..3 (16B units), returns u16 index
__device__ __forceinline__ int swz32(int row, int chunk) {
  return row * 32 + ((chunk ^ ((row >> 1) & 3)) << 3);
}
// swizzle for [rows][64] bf16 tiles (128B rows): colByte within row, returns u16 index
__device__ __forceinline__ int swz64(int row, int colByte) {
  return (row * 128 + (colByte ^ ((row & 7) << 4))) >> 1;
}

// ---------------- GEMM core: C[BM x BN] tile, K=512 (lda=ldb=512), BK=32, gload_lds ----
template<int BM, int BN>
__device__ __forceinline__ void gemm_core(const u16* __restrict__ A, const u16* __restrict__ Bt,
                                          int m0, int n0, f32x4 (&acc)[BM/32][BN/32],
                                          u16* lA, u16* lB) {
  const int t = threadIdx.x;
  const int lane = t & 63;
  const int w = t >> 6, wr = w >> 1, wc = w & 1;
  const int lr = lane & 15, lg = lane >> 4;
  char* lAb = (char*)lA + w * 1024;
  char* lBb = (char*)lB + w * 1024;
  #pragma unroll 1
  for (int k0 = 0; k0 < 512; k0 += 32) {
    __syncthreads();
    #pragma unroll
    for (int u = 0; u < BM / 64; ++u) {
      int id = u * 256 + t, row = id >> 2, gc = (id & 3) ^ ((row >> 1) & 3);
      gload16(A + (size_t)(m0 + row) * 512 + k0 + gc * 8, lAb + u * 4096);
    }
    #pragma unroll
    for (int u = 0; u < BN / 64; ++u) {
      int id = u * 256 + t, row = id >> 2, gc = (id & 3) ^ ((row >> 1) & 3);
      gload16(Bt + (size_t)(n0 + row) * 512 + k0 + gc * 8, lBb + u * 4096);
    }
    __syncthreads();
    bf16x8 af[BM / 32], bfr[BN / 32];
    #pragma unroll
    for (int i = 0; i < BM / 32; ++i)
      af[i] = __builtin_bit_cast(bf16x8, *(const uint4*)&lA[swz32(wr * (BM / 2) + i * 16 + lr, lg)]);
    #pragma unroll
    for (int j = 0; j < BN / 32; ++j)
      bfr[j] = __builtin_bit_cast(bf16x8, *(const uint4*)&lB[swz32(wc * (BN / 2) + j * 16 + lr, lg)]);
    #pragma unroll
    for (int i = 0; i < BM / 32; ++i)
      #pragma unroll
      for (int j = 0; j < BN / 32; ++j)
        acc[i][j] = __builtin_amdgcn_mfma_f32_16x16x32_bf16(af[i], bfr[j], acc[i][j], 0, 0, 0);
  }
}

// ---------------- QKV GEMM (128x64 tile) + scatter into Q(log2-scaled), K, V^T --------
__global__ __launch_bounds__(256, 2) void k_gemm_qkv(const u16* __restrict__ A, const u16* __restrict__ Bt,
                                                     const float* __restrict__ bias,
                                                     u16* __restrict__ Qb, u16* __restrict__ Kb,
                                                     u16* __restrict__ Vtb) {
  __shared__ __align__(16) u16 lA[128 * 32];
  __shared__ __align__(16) u16 lB[64 * 32];
  f32x4 acc[4][2];
  #pragma unroll
  for (int i = 0; i < 4; ++i)
    #pragma unroll
    for (int j = 0; j < 2; ++j) acc[i][j] = (f32x4){0.f, 0.f, 0.f, 0.f};
  const int m0 = blockIdx.x * 128, n0 = blockIdx.y * 64;
  gemm_core<128, 64>(A, Bt, m0, n0, acc, lA, lB);
  const int lane = threadIdx.x & 63;
  const int w = threadIdx.x >> 6, wr = w >> 1, wc = w & 1;
  const int lr = lane & 15, lg = lane >> 4;
  const float QSC = 0.18033688011112042f;  // 0.125 * log2(e)
  #pragma unroll
  for (int i = 0; i < 4; ++i)
    #pragma unroll
    for (int j = 0; j < 2; ++j)
      #pragma unroll
      for (int r = 0; r < 4; ++r) {
        int m = m0 + wr * 64 + i * 16 + lg * 4 + r;
        int n = n0 + wc * 32 + j * 16 + lr;
        float val = acc[i][j][r] + bias[n];
        int b = m >> 11, npos = m & 2047;
        int which = n >> 9, h = (n >> 6) & 7, hd = n & 63;
        size_t bh = (size_t)(b * 8 + h);
        if (which == 0)      Qb[(bh * 2048 + npos) * 64 + hd] = f2bf(val * QSC);
        else if (which == 1) Kb[(bh * 2048 + npos) * 64 + hd] = f2bf(val);
        else                 Vtb[(bh * 64 + hd) * 2048 + npos] = f2bf(val);
      }
}

// ---------------- proj GEMM (64x64 tile) -> fp32 output ----------------
__global__ __launch_bounds__(256, 2) void k_gemm_proj(const u16* __restrict__ A, const u16* __restrict__ Bt,
                                                      const float* __restrict__ bias,
                                                      float* __restrict__ out) {
  __shared__ __align__(16) u16 lA[64 * 32];
  __shared__ __align__(16) u16 lB[64 * 32];
  f32x4 acc[2][2];
  #pragma unroll
  for (int i = 0; i < 2; ++i)
    #pragma unroll
    for (int j = 0; j < 2; ++j) acc[i][j] = (f32x4){0.f, 0.f, 0.f, 0.f};
  const int m0 = blockIdx.x * 64, n0 = blockIdx.y * 64;
  gemm_core<64, 64>(A, Bt, m0, n0, acc, lA, lB);
  const int lane = threadIdx.x & 63;
  const int w = threadIdx.x >> 6, wr = w >> 1, wc = w & 1;
  const int lr = lane & 15, lg = lane >> 4;
  #pragma unroll
  for (int i = 0; i < 2; ++i)
    #pragma unroll
    for (int j = 0; j < 2; ++j)
      #pragma unroll
      for (int r = 0; r < 4; ++r) {
        int m = m0 + wr * 32 + i * 16 + lg * 4 + r;
        int n = n0 + wc * 32 + j * 16 + lr;
        out[(size_t)m * 512 + n] = acc[i][j][r] + bias[n];
      }
}

// ---------------- flash attention, swapped-operand, KV-split=4 ----------------
// Per lane: one q-row (lane&15). S/softmax/P/O all lane-local in q.
// Writes unnormalized fp16 O partials + per-row m,l (log2 domain).
__global__ __launch_bounds__(256, 4) void k_attn(const u16* __restrict__ Qb, const u16* __restrict__ Kb,
                                                 const u16* __restrict__ Vtb,
                                                 u16* __restrict__ Op, float* __restrict__ Mp,
                                                 float* __restrict__ Lp) {
  __shared__ __align__(16) u16 Kt[64 * 64];      // [s][hd], swizzled
  __shared__ __align__(16) u16 Vl[64 * 64];      // [hd][s], swizzled
  __shared__ __align__(16) u16 Pl[4][16 * 64];   // per-wave P tile [q][s], swizzled
  const int t = threadIdx.x;
  const int lane = t & 63, w = t >> 6;
  const int lr = lane & 15, lg = lane >> 4;
  const int qtile = blockIdx.x, bh = blockIdx.y, split = blockIdx.z;
  const int q0 = qtile * 64 + w * 16;
  const int sBeg = split * 512;

  bf16x8 qf0, qf1;  // B-operand frags: col=q (lane&15), k-slice lg
  {
    const u16* qrow = Qb + ((size_t)bh * 2048 + q0 + lr) * 64;
    qf0 = __builtin_bit_cast(bf16x8, *(const uint4*)(qrow + lg * 8));
    qf1 = __builtin_bit_cast(bf16x8, *(const uint4*)(qrow + 32 + lg * 8));
  }

  float m_run = -1e30f, l_run = 0.f;
  f32x4 oacc[4];
  #pragma unroll
  for (int f = 0; f < 4; ++f) oacc[f] = (f32x4){0.f, 0.f, 0.f, 0.f};

  const int r0_ = t >> 3, o0 = (t & 7) << 3;
  const int r1_ = r0_ + 32;
  const int s0i = swz64(r0_, o0 * 2), s1i = swz64(r1_, o0 * 2);
  const u16* Kbase = Kb + (size_t)bh * 2048 * 64;
  const u16* Vbase = Vtb + (size_t)bh * 64 * 2048;
  u16* pw = Pl[w];

  // prologue: prefetch tile 0 into registers
  uint4 kq0 = *(const uint4*)(Kbase + (size_t)(sBeg + r0_) * 64 + o0);
  uint4 kq1 = *(const uint4*)(Kbase + (size_t)(sBeg + r1_) * 64 + o0);
  uint4 vq0 = *(const uint4*)(Vbase + (size_t)r0_ * 2048 + sBeg + o0);
  uint4 vq1 = *(const uint4*)(Vbase + (size_t)r1_ * 2048 + sBeg + o0);

  #pragma unroll 1
  for (int s0 = sBeg; s0 < sBeg + 512; s0 += 64) {
    __syncthreads();
    *(uint4*)&Kt[s0i] = kq0; *(uint4*)&Kt[s1i] = kq1;
    *(uint4*)&Vl[s0i] = vq0; *(uint4*)&Vl[s1i] = vq1;
    __syncthreads();
    if (s0 + 64 < sBeg + 512) {
      int sn = s0 + 64;
      kq0 = *(const uint4*)(Kbase + (size_t)(sn + r0_) * 64 + o0);
      kq1 = *(const uint4*)(Kbase + (size_t)(sn + r1_) * 64 + o0);
      vq0 = *(const uint4*)(Vbase + (size_t)r0_ * 2048 + sn + o0);
      vq1 = *(const uint4*)(Vbase + (size_t)r1_ * 2048 + sn + o0);
    }

    // S^T = K Q^T : D[col=q(lane&15)][row=s_local(lg*4+r)] per jf group of 16 s
    f32x4 sa[4];
    #pragma unroll
    for (int jf = 0; jf < 4; ++jf) {
      bf16x8 kb0 = __builtin_bit_cast(bf16x8, *(const uint4*)&Kt[swz64(jf * 16 + lr, lg * 16)]);
      bf16x8 kb1 = __builtin_bit_cast(bf16x8, *(const uint4*)&Kt[swz64(jf * 16 + lr, 64 + lg * 16)]);
      f32x4 z = (f32x4){0.f, 0.f, 0.f, 0.f};
      z = __builtin_amdgcn_mfma_f32_16x16x32_bf16(kb0, qf0, z, 0, 0, 0);
      z = __builtin_amdgcn_mfma_f32_16x16x32_bf16(kb1, qf1, z, 0, 0, 0);
      sa[jf] = z;
    }

    // in-lane online softmax (16 s-values per lane, cross-lg via 2 shfls)
    float tm = fmaxf(fmaxf(fmaxf(sa[0][0], sa[0][1]), fmaxf(sa[0][2], sa[0][3])),
                     fmaxf(fmaxf(sa[1][0], sa[1][1]), fmaxf(sa[1][2], sa[1][3])));
    tm = fmaxf(tm, fmaxf(fmaxf(fmaxf(sa[2][0], sa[2][1]), fmaxf(sa[2][2], sa[2][3])),
                         fmaxf(fmaxf(sa[3][0], sa[3][1]), fmaxf(sa[3][2], sa[3][3]))));
    tm = fmaxf(tm, __shfl_xor(tm, 16));
    tm = fmaxf(tm, __shfl_xor(tm, 32));
    float mnew = fmaxf(m_run, tm);
    float fac = exp2f(m_run - mnew);
    m_run = mnew;
    #pragma unroll
    for (int jf = 0; jf < 4; ++jf)
      #pragma unroll
      for (int r = 0; r < 4; ++r)
        sa[jf][r] = exp2f(sa[jf][r] - mnew);
    f32x4 ps = sa[0] + sa[1] + sa[2] + sa[3];
    float rs = (ps[0] + ps[1]) + (ps[2] + ps[3]);
    rs += __shfl_xor(rs, 16);
    rs += __shfl_xor(rs, 32);
    l_run = l_run * fac + rs;
    #pragma unroll
    for (int f = 0; f < 4; ++f) oacc[f] *= fac;

    // P pack: lane's q-row, s = jf*16 + lg*4 + r -> b64 writes
    #pragma unroll
    for (int jf = 0; jf < 4; ++jf) {
      bf16x4 pv;
      pv[0] = (__bf16)sa[jf][0]; pv[1] = (__bf16)sa[jf][1];
      pv[2] = (__bf16)sa[jf][2]; pv[3] = (__bf16)sa[jf][3];
      *(uint2*)&pw[swz64(lr, jf * 32 + lg * 8)] = __builtin_bit_cast(uint2, pv);
    }
    asm volatile("s_waitcnt lgkmcnt(0)" ::: "memory");

    // O^T += V P^T : D[col=q][row=hd_local], B-operand P read lane-local in q
    #pragma unroll
    for (int kw = 0; kw < 2; ++kw) {
      bf16x8 pb = __builtin_bit_cast(bf16x8, *(const uint4*)&pw[swz64(lr, kw * 64 + lg * 16)]);
      #pragma unroll
      for (int f = 0; f < 4; ++f) {
        bf16x8 vb = __builtin_bit_cast(bf16x8, *(const uint4*)&Vl[swz64(f * 16 + lr, kw * 64 + lg * 16)]);
        oacc[f] = __builtin_amdgcn_mfma_f32_16x16x32_bf16(vb, pb, oacc[f], 0, 0, 0);
      }
    }
  }

  // epilogue: unnormalized fp16 partials; hd = f*16 + lg*4 + r, q = lr
  const size_t orow = (size_t)((split * 16 + bh) * 2048) + q0 + lr;
  #pragma unroll
  for (int f = 0; f < 4; ++f) {
    f16x4 hv;
    hv[0] = (_Float16)oacc[f][0]; hv[1] = (_Float16)oacc[f][1];
    hv[2] = (_Float16)oacc[f][2]; hv[3] = (_Float16)oacc[f][3];
    *(uint2*)&Op[orow * 64 + f * 16 + lg * 4] = __builtin_bit_cast(uint2, hv);
  }
  if (lg == 0) { Mp[orow] = m_run; Lp[orow] = l_run; }
}

// ---------------- combine 4 KV-splits -> AO (bf16, [b][q][h*64+hd]) ----------------
__global__ void k_combine(const u16* __restrict__ Op, const float* __restrict__ Mp,
                          const float* __restrict__ Lp, u16* __restrict__ AO) {
  int idx = blockIdx.x * 256 + threadIdx.x;  // 32768 rows * 8 chunks
  int chunk = idx & 7, row = idx >> 3;
  float m[4], l[4];
  #pragma unroll
  for (int s = 0; s < 4; ++s) { m[s] = Mp[s * 32768 + row]; l[s] = Lp[s * 32768 + row]; }
  float M = fmaxf(fmaxf(m[0], m[1]), fmaxf(m[2], m[3]));
  float ws[4], den = 0.f;
  #pragma unroll
  for (int s = 0; s < 4; ++s) { ws[s] = exp2f(m[s] - M); den += ws[s] * l[s]; }
  float inv = 1.0f / den;
  float o[8];
  #pragma unroll
  for (int k = 0; k < 8; ++k) o[k] = 0.f;
  #pragma unroll
  for (int s = 0; s < 4; ++s) {
    uint4 u = ((const uint4*)Op)[(size_t)s * 262144 + row * 8 + chunk];
    f16x8 hv = __builtin_bit_cast(f16x8, u);
    float wsc = ws[s];
    #pragma unroll
    for (int k = 0; k < 8; ++k) o[k] += wsc * (float)hv[k];
  }
  bf16x8 bv;
  #pragma unroll
  for (int k = 0; k < 8; ++k) bv[k] = (__bf16)(o[k] * inv);
  int bh = row >> 11, q = row & 2047, bb = bh >> 3, h = bh & 7;
  *(uint4*)&AO[((size_t)(bb * 2048 + q)) * 512 + h * 64 + chunk * 8] = __builtin_bit_cast(uint4, bv);
}

extern "C" void kernel_launch(void* const* d_in, const int* in_sizes, int n_in,
                              void* d_out, int out_size, void* d_ws, size_t ws_size,
                              hipStream_t stream) {
  (void)in_sizes; (void)n_in; (void)out_size; (void)ws_size;
  const float* x      = (const float*)d_in[0];
  const float* qkv_w  = (const float*)d_in[1];
  const float* qkv_b  = (const float*)d_in[2];
  const float* proj_w = (const float*)d_in[3];
  const float* proj_b = (const float*)d_in[4];
  float* out = (float*)d_out;
  char* wsc = (char*)d_ws;
  // Mp/Lp overlap the Xb region (Xb dead after k_gemm_qkv; Mp/Lp written by k_attn later).
  float* Mp  = (float*)(wsc + 0);        // [4][16][2048] f32 (524,288 B)
  float* Lp  = (float*)(wsc + 524288);   // [4][16][2048] f32 (524,288 B)
  u16*   Xb  = (u16*)(wsc + 0);          // 4096x512 bf16       (4,194,304 B)
  u16*   Wt  = (u16*)(wsc + 4194304);    // 1536x512 bf16 (W^T) (1,572,864 B)
  u16*   Pt  = (u16*)(wsc + 5767168);    // 512x512 bf16 (W^T)  (  524,288 B)
  u16*   Qb  = (u16*)(wsc + 6291456);    // [16][2048][64] bf16 (4,194,304 B)
  u16*   Kb  = (u16*)(wsc + 10485760);   // [16][2048][64] bf16
  u16*   Vtb = (u16*)(wsc + 14680064);   // [16][64][2048] bf16
  u16*   AO  = (u16*)(wsc + 18874368);   // 4096x512 bf16
  u16*   Op  = (u16*)(wsc + 23068672);   // [4][16][2048][64] fp16 (16,777,216 B) -> end 39,845,888

  k_prep<<<2304, 256, 0, stream>>>(x, qkv_w, proj_w, Xb, Wt, Pt);
  k_gemm_qkv<<<dim3(32, 24), 256, 0, stream>>>(Xb, Wt, qkv_b, Qb, Kb, Vtb);
  k_attn<<<dim3(32, 16, 4), 256, 0, stream>>>(Qb, Kb, Vtb, Op, Mp, Lp);
  k_combine<<<1024, 256, 0, stream>>>(Op, Mp, Lp, AO);
  k_gemm_proj<<<dim3(64, 8), 256, 0, stream>>>(AO, Pt, proj_b, out);
}

// Round 4
// 79.727 us; speedup vs baseline: 1.5218x; 1.0205x over previous
//
#include <hip/hip_runtime.h>
#include <stdint.h>

typedef unsigned short u16;
typedef __bf16 bf16x8 __attribute__((ext_vector_type(8)));
typedef __bf16 bf16x4 __attribute__((ext_vector_type(4)));
typedef short s16x4 __attribute__((ext_vector_type(4)));
typedef _Float16 f16x4 __attribute__((ext_vector_type(4)));
typedef _Float16 f16x8 __attribute__((ext_vector_type(8)));
typedef float  f32x4  __attribute__((ext_vector_type(4)));

__device__ __forceinline__ u16 f2bf(float f) {
  union { float f; unsigned u; } v; v.f = f;
  unsigned r = v.u + 0x7FFFu + ((v.u >> 16) & 1u);
  return (u16)(r >> 16);
}

__device__ __forceinline__ void gload16(const void* g, void* l) {
  __builtin_amdgcn_global_load_lds((const __attribute__((address_space(1))) unsigned int*)g,
                                   (__attribute__((address_space(3))) unsigned int*)l, 16, 0, 0);
}

// K=16 bf16 MFMA: B-operand k-map (k=lg*4+j) == QK^T D-layout (s=lg*4+r) -> P feeds
// PV directly from registers. Fallback: zero-padded K=32 (A,B agree on (lg,j)->s map;
// uncovered k slots have A=B=0 so contribute nothing).
__device__ __forceinline__ f32x4 mfma16(bf16x4 a, bf16x4 b, f32x4 c) {
#if __has_builtin(__builtin_amdgcn_mfma_f32_16x16x16bf16_1k)
  return __builtin_amdgcn_mfma_f32_16x16x16bf16_1k(__builtin_bit_cast(s16x4, a),
                                                   __builtin_bit_cast(s16x4, b), c, 0, 0, 0);
#else
  bf16x8 a8 = {a[0], a[1], a[2], a[3], (__bf16)0.f, (__bf16)0.f, (__bf16)0.f, (__bf16)0.f};
  bf16x8 b8 = {b[0], b[1], b[2], b[3], (__bf16)0.f, (__bf16)0.f, (__bf16)0.f, (__bf16)0.f};
  return __builtin_amdgcn_mfma_f32_16x16x32_bf16(a8, b8, c, 0, 0, 0);
#endif
}

// ---------------- fused prep: x->bf16 convert + both weight transposes ----------------
__global__ void k_prep(const float* __restrict__ x, const float* __restrict__ qw,
                       const float* __restrict__ pjw, u16* __restrict__ Xb,
                       u16* __restrict__ Wt, u16* __restrict__ Pt) {
  __shared__ u16 tile[64][65];
  const int b = blockIdx.x, t = threadIdx.x;
  if (b < 2048) {
    int i = b * 256 + t;
    float4 v = ((const float4*)x)[i];
    uint2 o;
    o.x = (unsigned)f2bf(v.x) | ((unsigned)f2bf(v.y) << 16);
    o.y = (unsigned)f2bf(v.z) | ((unsigned)f2bf(v.w) << 16);
    ((uint2*)Xb)[i] = o;
    return;
  }
  const float* in; u16* out; int Cc, bx, by;
  if (b < 2240) { in = qw;  out = Wt; Cc = 1536; bx = (b - 2048) % 24; by = (b - 2048) / 24; }
  else          { in = pjw; out = Pt; Cc = 512;  bx = (b - 2240) & 7;  by = (b - 2240) >> 3; }
  const int c0 = bx * 64, r0 = by * 64;
  #pragma unroll
  for (int i = 0; i < 16; ++i) {
    int idx = t + i * 256;
    int r = idx >> 6, c = idx & 63;
    tile[c][r] = f2bf(in[(size_t)(r0 + r) * Cc + c0 + c]);
  }
  __syncthreads();
  #pragma unroll
  for (int i = 0; i < 16; ++i) {
    int idx = t + i * 256;
    int r = idx >> 6, c = idx & 63;
    out[(size_t)(c0 + r) * 512 + r0 + c] = tile[r][c];
  }
}

// swizzle for [rows][32] bf16 tiles: chunk 0..3 (16B units), returns u16 index
__device__ __forceinline__ int swz32(int row, int chunk) {
  return row * 32 + ((chunk ^ ((row >> 1) & 3)) << 3);
}
// swizzle for [rows][64] bf16 tiles (128B rows): colByte within row, returns u16 index
__device__ __forceinline__ int swz64(int row, int colByte) {
  return (row * 128 + (colByte ^ ((row & 7) << 4))) >> 1;
}

// ---------------- GEMM core: C[BM x BN] tile, K=512 (lda=ldb=512), BK=32, gload_lds ----
template<int BM, int BN>
__device__ __forceinline__ void gemm_core(const u16* __restrict__ A, const u16* __restrict__ Bt,
                                          int m0, int n0, f32x4 (&acc)[BM/32][BN/32],
                                          u16* lA, u16* lB) {
  const int t = threadIdx.x;
  const int lane = t & 63;
  const int w = t >> 6, wr = w >> 1, wc = w & 1;
  const int lr = lane & 15, lg = lane >> 4;
  char* lAb = (char*)lA + w * 1024;
  char* lBb = (char*)lB + w * 1024;
  #pragma unroll 1
  for (int k0 = 0; k0 < 512; k0 += 32) {
    __syncthreads();
    #pragma unroll
    for (int u = 0; u < BM / 64; ++u) {
      int id = u * 256 + t, row = id >> 2, gc = (id & 3) ^ ((row >> 1) & 3);
      gload16(A + (size_t)(m0 + row) * 512 + k0 + gc * 8, lAb + u * 4096);
    }
    #pragma unroll
    for (int u = 0; u < BN / 64; ++u) {
      int id = u * 256 + t, row = id >> 2, gc = (id & 3) ^ ((row >> 1) & 3);
      gload16(Bt + (size_t)(n0 + row) * 512 + k0 + gc * 8, lBb + u * 4096);
    }
    __syncthreads();
    bf16x8 af[BM / 32], bfr[BN / 32];
    #pragma unroll
    for (int i = 0; i < BM / 32; ++i)
      af[i] = __builtin_bit_cast(bf16x8, *(const uint4*)&lA[swz32(wr * (BM / 2) + i * 16 + lr, lg)]);
    #pragma unroll
    for (int j = 0; j < BN / 32; ++j)
      bfr[j] = __builtin_bit_cast(bf16x8, *(const uint4*)&lB[swz32(wc * (BN / 2) + j * 16 + lr, lg)]);
    #pragma unroll
    for (int i = 0; i < BM / 32; ++i)
      #pragma unroll
      for (int j = 0; j < BN / 32; ++j)
        acc[i][j] = __builtin_amdgcn_mfma_f32_16x16x32_bf16(af[i], bfr[j], acc[i][j], 0, 0, 0);
  }
}

// ---------------- QKV GEMM (128x64 tile) + scatter into Q(log2-scaled), K, V^T --------
__global__ __launch_bounds__(256, 2) void k_gemm_qkv(const u16* __restrict__ A, const u16* __restrict__ Bt,
                                                     const float* __restrict__ bias,
                                                     u16* __restrict__ Qb, u16* __restrict__ Kb,
                                                     u16* __restrict__ Vtb) {
  __shared__ __align__(16) u16 lA[128 * 32];
  __shared__ __align__(16) u16 lB[64 * 32];
  f32x4 acc[4][2];
  #pragma unroll
  for (int i = 0; i < 4; ++i)
    #pragma unroll
    for (int j = 0; j < 2; ++j) acc[i][j] = (f32x4){0.f, 0.f, 0.f, 0.f};
  const int m0 = blockIdx.x * 128, n0 = blockIdx.y * 64;
  gemm_core<128, 64>(A, Bt, m0, n0, acc, lA, lB);
  const int lane = threadIdx.x & 63;
  const int w = threadIdx.x >> 6, wr = w >> 1, wc = w & 1;
  const int lr = lane & 15, lg = lane >> 4;
  const float QSC = 0.18033688011112042f;  // 0.125 * log2(e)
  #pragma unroll
  for (int i = 0; i < 4; ++i)
    #pragma unroll
    for (int j = 0; j < 2; ++j)
      #pragma unroll
      for (int r = 0; r < 4; ++r) {
        int m = m0 + wr * 64 + i * 16 + lg * 4 + r;
        int n = n0 + wc * 32 + j * 16 + lr;
        float val = acc[i][j][r] + bias[n];
        int b = m >> 11, npos = m & 2047;
        int which = n >> 9, h = (n >> 6) & 7, hd = n & 63;
        size_t bh = (size_t)(b * 8 + h);
        if (which == 0)      Qb[(bh * 2048 + npos) * 64 + hd] = f2bf(val * QSC);
        else if (which == 1) Kb[(bh * 2048 + npos) * 64 + hd] = f2bf(val);
        else                 Vtb[(bh * 64 + hd) * 2048 + npos] = f2bf(val);
      }
}

// ---------------- proj GEMM (64x64 tile) -> fp32 output ----------------
__global__ __launch_bounds__(256, 2) void k_gemm_proj(const u16* __restrict__ A, const u16* __restrict__ Bt,
                                                      const float* __restrict__ bias,
                                                      float* __restrict__ out) {
  __shared__ __align__(16) u16 lA[64 * 32];
  __shared__ __align__(16) u16 lB[64 * 32];
  f32x4 acc[2][2];
  #pragma unroll
  for (int i = 0; i < 2; ++i)
    #pragma unroll
    for (int j = 0; j < 2; ++j) acc[i][j] = (f32x4){0.f, 0.f, 0.f, 0.f};
  const int m0 = blockIdx.x * 64, n0 = blockIdx.y * 64;
  gemm_core<64, 64>(A, Bt, m0, n0, acc, lA, lB);
  const int lane = threadIdx.x & 63;
  const int w = threadIdx.x >> 6, wr = w >> 1, wc = w & 1;
  const int lr = lane & 15, lg = lane >> 4;
  #pragma unroll
  for (int i = 0; i < 2; ++i)
    #pragma unroll
    for (int j = 0; j < 2; ++j)
      #pragma unroll
      for (int r = 0; r < 4; ++r) {
        int m = m0 + wr * 32 + i * 16 + lg * 4 + r;
        int n = n0 + wc * 32 + j * 16 + lr;
        out[(size_t)m * 512 + n] = acc[i][j][r] + bias[n];
      }
}

// ---------------- flash attention, swapped-operand, KV-split=4, LDS dbuf -------------
// Per lane: one q-row (lane&15). S/softmax/P/O all lane-local. P feeds PV via K=16 MFMA
// (no LDS round-trip); l via ones-operand MFMA; defer-max; 1 barrier/tile.
__global__ __launch_bounds__(256, 4) void k_attn(const u16* __restrict__ Qb, const u16* __restrict__ Kb,
                                                 const u16* __restrict__ Vtb,
                                                 u16* __restrict__ Op, float* __restrict__ Mp,
                                                 float* __restrict__ Lp) {
  __shared__ __align__(16) u16 Kt[2][64 * 64];   // [s][hd], swizzled
  __shared__ __align__(16) u16 Vl[2][64 * 64];   // [hd][s], swizzled
  const int t = threadIdx.x;
  const int lane = t & 63, w = t >> 6;
  const int lr = lane & 15, lg = lane >> 4;
  const int qtile = blockIdx.x, bh = blockIdx.y, split = blockIdx.z;
  const int q0 = qtile * 64 + w * 16;
  const int sBeg = split * 512;

  bf16x8 qf0, qf1;  // B-operand frags: col=q (lane&15), k-slice lg
  {
    const u16* qrow = Qb + ((size_t)bh * 2048 + q0 + lr) * 64;
    qf0 = __builtin_bit_cast(bf16x8, *(const uint4*)(qrow + lg * 8));
    qf1 = __builtin_bit_cast(bf16x8, *(const uint4*)(qrow + 32 + lg * 8));
  }

  float m_run = -1e30f;
  f32x4 oacc[4], lacc = (f32x4){0.f, 0.f, 0.f, 0.f};
  #pragma unroll
  for (int f = 0; f < 4; ++f) oacc[f] = (f32x4){0.f, 0.f, 0.f, 0.f};
  bf16x4 ones;
  ones[0] = (__bf16)1.f; ones[1] = (__bf16)1.f; ones[2] = (__bf16)1.f; ones[3] = (__bf16)1.f;

  const int r0_ = t >> 3, o0 = (t & 7) << 3;
  const int r1_ = r0_ + 32;
  const int s0i = swz64(r0_, o0 * 2), s1i = swz64(r1_, o0 * 2);
  const u16* Kbase = Kb + (size_t)bh * 2048 * 64;
  const u16* Vbase = Vtb + (size_t)bh * 64 * 2048;
  const u16* kp0 = Kbase + (size_t)(sBeg + r0_) * 64 + o0;
  const u16* kp1 = Kbase + (size_t)(sBeg + r1_) * 64 + o0;
  const u16* vp0 = Vbase + (size_t)r0_ * 2048 + sBeg + o0;
  const u16* vp1 = Vbase + (size_t)r1_ * 2048 + sBeg + o0;

  uint4 kq0, kq1, vq0, vq1;
  // prologue: tile0 -> regs -> buf0; tile1 -> regs
  kq0 = *(const uint4*)kp0; kq1 = *(const uint4*)kp1;
  vq0 = *(const uint4*)vp0; vq1 = *(const uint4*)vp1;
  kp0 += 4096; kp1 += 4096; vp0 += 64; vp1 += 64;
  *(uint4*)&Kt[0][s0i] = kq0; *(uint4*)&Kt[0][s1i] = kq1;
  *(uint4*)&Vl[0][s0i] = vq0; *(uint4*)&Vl[0][s1i] = vq1;
  kq0 = *(const uint4*)kp0; kq1 = *(const uint4*)kp1;
  vq0 = *(const uint4*)vp0; vq1 = *(const uint4*)vp1;
  kp0 += 4096; kp1 += 4096; vp0 += 64; vp1 += 64;

  auto TILE = [&](u16* KC, u16* VC, u16* KN, u16* VN) {
    __syncthreads();  // buf KC/VC fully staged; KN/VN free to overwrite
    // S^T = K Q^T : lane holds S[s=jf*16+lg*4+r][q=lr]
    f32x4 sa[4];
    __builtin_amdgcn_s_setprio(1);
    #pragma unroll
    for (int jf = 0; jf < 4; ++jf) {
      bf16x8 kb0 = __builtin_bit_cast(bf16x8, *(const uint4*)&KC[swz64(jf * 16 + lr, lg * 16)]);
      bf16x8 kb1 = __builtin_bit_cast(bf16x8, *(const uint4*)&KC[swz64(jf * 16 + lr, 64 + lg * 16)]);
      f32x4 z = (f32x4){0.f, 0.f, 0.f, 0.f};
      z = __builtin_amdgcn_mfma_f32_16x16x32_bf16(kb0, qf0, z, 0, 0, 0);
      z = __builtin_amdgcn_mfma_f32_16x16x32_bf16(kb1, qf1, z, 0, 0, 0);
      sa[jf] = z;
    }
    __builtin_amdgcn_s_setprio(0);
    // stage next tile (regs -> LDS), then prefetch tile+2 (global -> regs)
    *(uint4*)&KN[s0i] = kq0; *(uint4*)&KN[s1i] = kq1;
    *(uint4*)&VN[s0i] = vq0; *(uint4*)&VN[s1i] = vq1;
    kq0 = *(const uint4*)kp0; kq1 = *(const uint4*)kp1;
    vq0 = *(const uint4*)vp0; vq1 = *(const uint4*)vp1;
    kp0 += 4096; kp1 += 4096; vp0 += 64; vp1 += 64;
    // online softmax with defer-max (THR=4 in log2 domain)
    float tm = fmaxf(fmaxf(fmaxf(sa[0][0], sa[0][1]), fmaxf(sa[0][2], sa[0][3])),
                     fmaxf(fmaxf(sa[1][0], sa[1][1]), fmaxf(sa[1][2], sa[1][3])));
    tm = fmaxf(tm, fmaxf(fmaxf(fmaxf(sa[2][0], sa[2][1]), fmaxf(sa[2][2], sa[2][3])),
                         fmaxf(fmaxf(sa[3][0], sa[3][1]), fmaxf(sa[3][2], sa[3][3]))));
    tm = fmaxf(tm, __shfl_xor(tm, 16));
    tm = fmaxf(tm, __shfl_xor(tm, 32));
    if (__any(tm > m_run + 4.0f)) {
      float mnew = fmaxf(m_run, tm);
      float fac = exp2f(m_run - mnew);
      m_run = mnew;
      #pragma unroll
      for (int f = 0; f < 4; ++f) oacc[f] *= fac;
      lacc *= fac;
    }
    bf16x4 pb[4];
    #pragma unroll
    for (int jf = 0; jf < 4; ++jf) {
      #pragma unroll
      for (int r = 0; r < 4; ++r) sa[jf][r] = exp2f(sa[jf][r] - m_run);
      pb[jf][0] = (__bf16)sa[jf][0]; pb[jf][1] = (__bf16)sa[jf][1];
      pb[jf][2] = (__bf16)sa[jf][2]; pb[jf][3] = (__bf16)sa[jf][3];
    }
    // O^T += V P^T (K=16, P lane-local); l via ones-row MFMA
    __builtin_amdgcn_s_setprio(1);
    #pragma unroll
    for (int jf = 0; jf < 4; ++jf) {
      lacc = mfma16(ones, pb[jf], lacc);
      #pragma unroll
      for (int f = 0; f < 4; ++f) {
        bf16x4 va = __builtin_bit_cast(bf16x4, *(const uint2*)&VC[swz64(f * 16 + lr, jf * 32 + lg * 8)]);
        oacc[f] = mfma16(va, pb[jf], oacc[f]);
      }
    }
    __builtin_amdgcn_s_setprio(0);
  };

  #pragma unroll 1
  for (int tt = 0; tt < 4; ++tt) {
    TILE(Kt[0], Vl[0], Kt[1], Vl[1]);
    TILE(Kt[1], Vl[1], Kt[0], Vl[0]);
  }

  // epilogue: unnormalized fp16 partials; hd = f*16 + lg*4 + r, q = lr
  const float l_run = lacc[0];
  const size_t orow = (size_t)((split * 16 + bh) * 2048) + q0 + lr;
  #pragma unroll
  for (int f = 0; f < 4; ++f) {
    f16x4 hv;
    hv[0] = (_Float16)oacc[f][0]; hv[1] = (_Float16)oacc[f][1];
    hv[2] = (_Float16)oacc[f][2]; hv[3] = (_Float16)oacc[f][3];
    *(uint2*)&Op[orow * 64 + f * 16 + lg * 4] = __builtin_bit_cast(uint2, hv);
  }
  if (lg == 0) { Mp[orow] = m_run; Lp[orow] = l_run; }
}

// ---------------- combine 4 KV-splits -> AO (bf16, [b][q][h*64+hd]) ----------------
__global__ void k_combine(const u16* __restrict__ Op, const float* __restrict__ Mp,
                          const float* __restrict__ Lp, u16* __restrict__ AO) {
  int idx = blockIdx.x * 256 + threadIdx.x;  // 32768 rows * 8 chunks
  int chunk = idx & 7, row = idx >> 3;
  float m[4], l[4];
  #pragma unroll
  for (int s = 0; s < 4; ++s) { m[s] = Mp[s * 32768 + row]; l[s] = Lp[s * 32768 + row]; }
  float M = fmaxf(fmaxf(m[0], m[1]), fmaxf(m[2], m[3]));
  float ws[4], den = 0.f;
  #pragma unroll
  for (int s = 0; s < 4; ++s) { ws[s] = exp2f(m[s] - M); den += ws[s] * l[s]; }
  float inv = 1.0f / den;
  float o[8];
  #pragma unroll
  for (int k = 0; k < 8; ++k) o[k] = 0.f;
  #pragma unroll
  for (int s = 0; s < 4; ++s) {
    uint4 u = ((const uint4*)Op)[(size_t)s * 262144 + row * 8 + chunk];
    f16x8 hv = __builtin_bit_cast(f16x8, u);
    float wsc = ws[s];
    #pragma unroll
    for (int k = 0; k < 8; ++k) o[k] += wsc * (float)hv[k];
  }
  bf16x8 bv;
  #pragma unroll
  for (int k = 0; k < 8; ++k) bv[k] = (__bf16)(o[k] * inv);
  int bh = row >> 11, q = row & 2047, bb = bh >> 3, h = bh & 7;
  *(uint4*)&AO[((size_t)(bb * 2048 + q)) * 512 + h * 64 + chunk * 8] = __builtin_bit_cast(uint4, bv);
}

extern "C" void kernel_launch(void* const* d_in, const int* in_sizes, int n_in,
                              void* d_out, int out_size, void* d_ws, size_t ws_size,
                              hipStream_t stream) {
  (void)in_sizes; (void)n_in; (void)out_size; (void)ws_size;
  const float* x      = (const float*)d_in[0];
  const float* qkv_w  = (const float*)d_in[1];
  const float* qkv_b  = (const float*)d_in[2];
  const float* proj_w = (const float*)d_in[3];
  const float* proj_b = (const float*)d_in[4];
  float* out = (float*)d_out;
  char* wsc = (char*)d_ws;
  // Mp/Lp overlap the Xb region (Xb dead after k_gemm_qkv; Mp/Lp written by k_attn later).
  float* Mp  = (float*)(wsc + 0);        // [4][16][2048] f32 (524,288 B)
  float* Lp  = (float*)(wsc + 524288);   // [4][16][2048] f32 (524,288 B)
  u16*   Xb  = (u16*)(wsc + 0);          // 4096x512 bf16       (4,194,304 B)
  u16*   Wt  = (u16*)(wsc + 4194304);    // 1536x512 bf16 (W^T) (1,572,864 B)
  u16*   Pt  = (u16*)(wsc + 5767168);    // 512x512 bf16 (W^T)  (  524,288 B)
  u16*   Qb  = (u16*)(wsc + 6291456);    // [16][2048][64] bf16 (4,194,304 B)
  u16*   Kb  = (u16*)(wsc + 10485760);   // [16][2048][64] bf16
  u16*   Vtb = (u16*)(wsc + 14680064);   // [16][64][2048] bf16
  u16*   AO  = (u16*)(wsc + 18874368);   // 4096x512 bf16
  u16*   Op  = (u16*)(wsc + 23068672);   // [4][16][2048][64] fp16 (16,777,216 B) -> end 39,845,888

  k_prep<<<2304, 256, 0, stream>>>(x, qkv_w, proj_w, Xb, Wt, Pt);
  k_gemm_qkv<<<dim3(32, 24), 256, 0, stream>>>(Xb, Wt, qkv_b, Qb, Kb, Vtb);
  k_attn<<<dim3(32, 16, 4), 256, 0, stream>>>(Qb, Kb, Vtb, Op, Mp, Lp);
  k_combine<<<1024, 256, 0, stream>>>(Op, Mp, Lp, AO);
  k_gemm_proj<<<dim3(64, 8), 256, 0, stream>>>(AO, Pt, proj_b, out);
}